// Round 1
// baseline (1059.487 us; speedup 1.0000x reference)
//
#include <hip/hip_runtime.h>

#define TOTAL_TOKENS 16384
#define D_MODEL 4096
#define VOCAB 50257
#define NUM_SEQS 32

// ws layout:
//   [0,128)        idx[32] int
//   [256,512)      keys[32] u64 (argmax atomics)
//   [1024, +512KB) hT [4096][32] float  (transposed gathered hidden rows)

__global__ void k_prep(const int* __restrict__ lens, int* __restrict__ idx,
                       unsigned long long* __restrict__ keys) {
  int t = threadIdx.x;
  if (t == 0) {
    int run = 0;
    for (int s = 0; s < NUM_SEQS; ++s) { run += lens[s]; idx[s] = run - 1; }
  }
  if (t < NUM_SEQS) keys[t] = 0ull;
}

// grid: D_MODEL/16 = 256 blocks x 512 threads. Block b covers k in [b*16, b*16+16).
// Reads: each block pulls exactly one 64B line per hidden row (32 rows x 64B).
// Writes: hT[k*32+s], lanes sweep s => 128B contiguous per 32 lanes, coalesced.
__global__ void k_gather(const float* __restrict__ hs, const int* __restrict__ idx,
                         float* __restrict__ hT) {
  int t = threadIdx.x;            // 0..511
  int s = t & 31;
  int k = blockIdx.x * 16 + (t >> 5);
  int row = idx[s];
  hT[k * 32 + s] = hs[(size_t)row * D_MODEL + k];
}

// One vocab row per lane. 786 blocks x 64 threads.
__global__ __launch_bounds__(64) void k_logits(const float* __restrict__ W,
                                               const float* __restrict__ hT,
                                               unsigned long long* __restrict__ keys) {
  int v = blockIdx.x * 64 + threadIdx.x;
  int vc = v < VOCAB ? v : VOCAB - 1;
  const float4* wr = (const float4*)(W + (size_t)vc * D_MODEL);

  float acc[NUM_SEQS];
#pragma unroll
  for (int s = 0; s < NUM_SEQS; ++s) acc[s] = 0.f;

  // software double-buffer: one full 64B line (4 x float4) per lane in flight
  float4 cur0 = wr[0], cur1 = wr[1], cur2 = wr[2], cur3 = wr[3];

#pragma unroll 1
  for (int kq = 0; kq < 1024; kq += 4) {
    int nk = (kq + 4) & 1023;  // branchless: last iter redundantly reloads group 0
    float4 nxt0 = wr[nk], nxt1 = wr[nk + 1], nxt2 = wr[nk + 2], nxt3 = wr[nk + 3];
    const float* h = hT + kq * 128;  // 16 k-positions x 32 seqs, contiguous

#pragma unroll
    for (int kk = 0; kk < 16; ++kk) {
      const float4 wq = (kk < 4) ? cur0 : (kk < 8) ? cur1 : (kk < 12) ? cur2 : cur3;
      const int c = kk & 3;
      const float wv = (c == 0) ? wq.x : (c == 1) ? wq.y : (c == 2) ? wq.z : wq.w;
      const float* hk = h + kk * 32;  // wave-uniform address -> s_load
#pragma unroll
      for (int s = 0; s < NUM_SEQS; ++s)
        acc[s] = fmaf(wv, hk[s], acc[s]);
    }
    cur0 = nxt0; cur1 = nxt1; cur2 = nxt2; cur3 = nxt3;
  }

  // per-seq wave argmax: key = ordered(logit)<<32 | ~v  (ties -> lowest v wins)
  unsigned key_lo = ~(unsigned)v;
  bool valid = (v < VOCAB);
#pragma unroll
  for (int s = 0; s < NUM_SEQS; ++s) {
    unsigned u = __float_as_uint(acc[s]);
    u = (u & 0x80000000u) ? ~u : (u | 0x80000000u);
    unsigned long long key = valid ? (((unsigned long long)u << 32) | key_lo) : 0ull;
#pragma unroll
    for (int off = 32; off > 0; off >>= 1) {
      unsigned long long other = __shfl_xor(key, off, 64);
      if (other > key) key = other;
    }
    if (threadIdx.x == 0) atomicMax(&keys[s], key);
  }
}

__global__ void k_final(const unsigned long long* __restrict__ keys,
                        int* __restrict__ out) {
  int s = threadIdx.x;
  if (s < NUM_SEQS) out[s] = (int)(~(unsigned)(keys[s] & 0xFFFFFFFFull));
}

extern "C" void kernel_launch(void* const* d_in, const int* in_sizes, int n_in,
                              void* d_out, int out_size, void* d_ws, size_t ws_size,
                              hipStream_t stream) {
  const float* hs  = (const float*)d_in[0];   // [16384][4096] f32
  const float* W   = (const float*)d_in[1];   // [50257][4096] f32
  const int* lens  = (const int*)d_in[2];     // [32] i32

  char* ws = (char*)d_ws;
  int* idx = (int*)ws;
  unsigned long long* keys = (unsigned long long*)(ws + 256);
  float* hT = (float*)(ws + 1024);
  int* out = (int*)d_out;

  k_prep<<<1, 64, 0, stream>>>(lens, idx, keys);
  k_gather<<<D_MODEL / 16, 512, 0, stream>>>(hs, idx, hT);
  int nblk = (VOCAB + 63) / 64;  // 786
  k_logits<<<nblk, 64, 0, stream>>>(W, hT, keys);
  k_final<<<1, 64, 0, stream>>>(keys, out);
}

// Round 2
// 419.575 us; speedup vs baseline: 2.5251x; 2.5251x over previous
//
#include <hip/hip_runtime.h>

#define D_MODEL 4096
#define VOCAB 50257
#define VOCAB_PAD 50304
#define NUM_SEQS 32
#define KSPLIT 4
#define KC (D_MODEL / KSPLIT)  // 1024 k-elements per wave

// ws layout:
//   [0,128)              idx[32] int
//   [1024, +512KB)       hT [4096][32] float (transposed gathered hidden rows)
//   [1<<20, +6.44MB)     logits [32][VOCAB_PAD] float (atomic accumulation planes)

__global__ void k_prep(const int* __restrict__ lens, int* __restrict__ idx) {
  if (threadIdx.x == 0) {
    int run = 0;
    for (int s = 0; s < NUM_SEQS; ++s) { run += lens[s]; idx[s] = run - 1; }
  }
}

// 256 blocks x 512 threads; block b covers k in [b*16, b*16+16)
__global__ void k_gather(const float* __restrict__ hs, const int* __restrict__ idx,
                         float* __restrict__ hT) {
  int t = threadIdx.x;
  int s = t & 31;
  int k = blockIdx.x * 16 + (t >> 5);
  int row = idx[s];
  hT[k * 32 + s] = hs[(size_t)row * D_MODEL + k];
}

// grid (786, KSPLIT) x 64 threads. One vocab row per lane, one K-chunk per block.y.
// h addresses are wave-uniform -> scalar loads; W rows stream per-lane (every
// fetched byte consumed). TLP (12 waves/CU) hides HBM latency.
__global__ __launch_bounds__(64) void k_logits_part(const float* __restrict__ W,
                                                    const float* __restrict__ hT,
                                                    float* __restrict__ logits) {
  int v = blockIdx.x * 64 + threadIdx.x;
  bool valid = (v < VOCAB);
  int vc = valid ? v : VOCAB - 1;
  int k0 = blockIdx.y * KC;
  const float4* wr = (const float4*)(W + (size_t)vc * D_MODEL + k0);
  const float* hbase = hT + (size_t)k0 * NUM_SEQS;

  float acc[NUM_SEQS];
#pragma unroll
  for (int s = 0; s < NUM_SEQS; ++s) acc[s] = 0.f;

#pragma unroll 1
  for (int kq = 0; kq < KC; kq += 16) {
    float wbuf[16];
    *(float4*)&wbuf[0]  = wr[(kq >> 2) + 0];
    *(float4*)&wbuf[4]  = wr[(kq >> 2) + 1];
    *(float4*)&wbuf[8]  = wr[(kq >> 2) + 2];
    *(float4*)&wbuf[12] = wr[(kq >> 2) + 3];
    const float* h = hbase + (size_t)kq * NUM_SEQS;
#pragma unroll
    for (int kk = 0; kk < 16; ++kk) {
      float wv = wbuf[kk];
      const float* hk = h + kk * NUM_SEQS;  // wave-uniform -> s_load_dwordx16
#pragma unroll
      for (int s = 0; s < NUM_SEQS; ++s)
        acc[s] = fmaf(wv, hk[s], acc[s]);
    }
  }

  if (valid) {
#pragma unroll
    for (int s = 0; s < NUM_SEQS; ++s)
      atomicAdd(&logits[(size_t)s * VOCAB_PAD + v], acc[s]);
  }
}

// 32 blocks (one per seq) x 256 threads; first-occurrence tie-break via ~v.
__global__ __launch_bounds__(256) void k_argmax(const float* __restrict__ logits,
                                                int* __restrict__ out) {
  int s = blockIdx.x;
  const float* row = logits + (size_t)s * VOCAB_PAD;
  unsigned long long best = 0ull;
  for (int v = threadIdx.x; v < VOCAB; v += 256) {
    float x = row[v];
    unsigned u = __float_as_uint(x);
    u = (u & 0x80000000u) ? ~u : (u | 0x80000000u);
    unsigned long long key = ((unsigned long long)u << 32) | (unsigned)(~v);
    if (key > best) best = key;
  }
#pragma unroll
  for (int off = 32; off > 0; off >>= 1) {
    unsigned long long o = __shfl_xor(best, off, 64);
    if (o > best) best = o;
  }
  __shared__ unsigned long long lred[4];
  if ((threadIdx.x & 63) == 0) lred[threadIdx.x >> 6] = best;
  __syncthreads();
  if (threadIdx.x == 0) {
#pragma unroll
    for (int i = 1; i < 4; ++i) if (lred[i] > best) best = lred[i];
    out[s] = (int)(~(unsigned)(best & 0xFFFFFFFFull));
  }
}

extern "C" void kernel_launch(void* const* d_in, const int* in_sizes, int n_in,
                              void* d_out, int out_size, void* d_ws, size_t ws_size,
                              hipStream_t stream) {
  const float* hs  = (const float*)d_in[0];   // [16384][4096] f32
  const float* W   = (const float*)d_in[1];   // [50257][4096] f32
  const int* lens  = (const int*)d_in[2];     // [32] i32

  char* ws = (char*)d_ws;
  int* idx = (int*)ws;
  float* hT = (float*)(ws + 1024);
  float* logits = (float*)(ws + (1 << 20));
  int* out = (int*)d_out;

  k_prep<<<1, 64, 0, stream>>>(lens, idx);
  k_gather<<<D_MODEL / 16, 512, 0, stream>>>(hs, idx, hT);
  hipMemsetAsync(logits, 0, (size_t)NUM_SEQS * VOCAB_PAD * sizeof(float), stream);
  dim3 grid((VOCAB + 63) / 64, KSPLIT);
  k_logits_part<<<grid, 64, 0, stream>>>(W, hT, logits);
  k_argmax<<<NUM_SEQS, 256, 0, stream>>>(logits, out);
}

// Round 3
// 302.739 us; speedup vs baseline: 3.4997x; 1.3859x over previous
//
#include <hip/hip_runtime.h>

#define D_MODEL 4096
#define VOCAB 50257
#define VP 50432            // padded vocab (197 * 256)
#define NUM_SEQS 32
#define KSPLIT 16
#define KC (D_MODEL / KSPLIT)   // 256 k per block
#define NSLICE 8

// ws layout:
//   [0,128)            idx[32] int
//   [1024, +512KB)     hT [4096][32] float (transposed gathered hidden rows)
//   [0x90000, +2KB)    partials [32][NSLICE] u64 argmax keys
//   [1MB, +103MB)      part [KSPLIT][32][VP] float partial-logit planes

__global__ void k_prep(const int* __restrict__ lens, int* __restrict__ idx) {
  if (threadIdx.x == 0) {
    int run = 0;
    for (int s = 0; s < NUM_SEQS; ++s) { run += lens[s]; idx[s] = run - 1; }
  }
}

// 256 blocks x 512 threads; block b covers k in [b*16, b*16+16)
__global__ void k_gather(const float* __restrict__ hs, const int* __restrict__ idx,
                         float* __restrict__ hT) {
  int t = threadIdx.x;
  int s = t & 31;
  int k = blockIdx.x * 16 + (t >> 5);
  int row = idx[s];
  hT[k * 32 + s] = hs[(size_t)row * D_MODEL + k];
}

// grid (197, KSPLIT) x 256. Block: 256 vocab rows (4 waves x 64), one 256-k chunk.
// h chunk staged in LDS; uniform ds_read_b128 broadcasts feed the FMAs.
__global__ __launch_bounds__(256, 4) void k_logits_part(
    const float* __restrict__ W, const float* __restrict__ hT,
    float* __restrict__ part) {
  __shared__ float hs_lds[KC * NUM_SEQS];  // 32 KB, layout [k][s]

  // linear 32KB copy: hs_lds[i] = hT[k0*32 + i]
  const int k0 = blockIdx.y * KC;
  {
    const float4* src = (const float4*)(hT + (size_t)k0 * NUM_SEQS);
    float4* dst = (float4*)hs_lds;
#pragma unroll
    for (int j = 0; j < (KC * NUM_SEQS / 4) / 256; ++j)
      dst[threadIdx.x + j * 256] = src[threadIdx.x + j * 256];
  }
  __syncthreads();

  const int v = blockIdx.x * 256 + threadIdx.x;   // wave w covers rows bx*256+w*64+lane
  const bool valid = (v < VOCAB);
  const int vc = valid ? v : VOCAB - 1;
  const float4* wr = (const float4*)(W + (size_t)vc * D_MODEL + k0);
  const float4* h4 = (const float4*)hs_lds;       // [k][s-quad]

  float acc[NUM_SEQS];
#pragma unroll
  for (int s = 0; s < NUM_SEQS; ++s) acc[s] = 0.f;

#pragma unroll 1
  for (int kq = 0; kq < KC; kq += 16) {
    float wbuf[16];
    *(float4*)&wbuf[0]  = wr[(kq >> 2) + 0];
    *(float4*)&wbuf[4]  = wr[(kq >> 2) + 1];
    *(float4*)&wbuf[8]  = wr[(kq >> 2) + 2];
    *(float4*)&wbuf[12] = wr[(kq >> 2) + 3];
#pragma unroll
    for (int kk = 0; kk < 16; ++kk) {
      const float wv = wbuf[kk];
#pragma unroll
      for (int sq = 0; sq < 8; ++sq) {
        const float4 hq = h4[((kq + kk) << 3) + sq];  // uniform -> broadcast
        acc[sq * 4 + 0] = fmaf(wv, hq.x, acc[sq * 4 + 0]);
        acc[sq * 4 + 1] = fmaf(wv, hq.y, acc[sq * 4 + 1]);
        acc[sq * 4 + 2] = fmaf(wv, hq.z, acc[sq * 4 + 2]);
        acc[sq * 4 + 3] = fmaf(wv, hq.w, acc[sq * 4 + 3]);
      }
    }
  }

  if (valid) {
    float* p = part + ((size_t)blockIdx.y * NUM_SEQS) * VP + v;
#pragma unroll
    for (int s = 0; s < NUM_SEQS; ++s) p[(size_t)s * VP] = acc[s];
  }
}

// grid (NSLICE, 32) x 256: block = (vocab slice, seq). Sums KSPLIT planes in
// fixed order (deterministic), tracks first-occurrence argmax key.
__global__ __launch_bounds__(256) void k_part_argmax(
    const float* __restrict__ part, unsigned long long* __restrict__ partials) {
  const int slice = blockIdx.x, s = blockIdx.y;
  const int v0 = slice * (VP / NSLICE);
  const int v1 = min(VOCAB, v0 + (VP / NSLICE));
  unsigned long long best = 0ull;
  for (int v = v0 + threadIdx.x; v < v1; v += 256) {
    float x = 0.f;
#pragma unroll
    for (int p = 0; p < KSPLIT; ++p)
      x += part[((size_t)p * NUM_SEQS + s) * VP + v];
    unsigned u = __float_as_uint(x);
    u = (u & 0x80000000u) ? ~u : (u | 0x80000000u);
    unsigned long long key = ((unsigned long long)u << 32) | (unsigned)(~v);
    if (key > best) best = key;
  }
#pragma unroll
  for (int off = 32; off > 0; off >>= 1) {
    unsigned long long o = __shfl_xor(best, off, 64);
    if (o > best) best = o;
  }
  __shared__ unsigned long long lred[4];
  if ((threadIdx.x & 63) == 0) lred[threadIdx.x >> 6] = best;
  __syncthreads();
  if (threadIdx.x == 0) {
#pragma unroll
    for (int i = 1; i < 4; ++i) if (lred[i] > best) best = lred[i];
    partials[s * NSLICE + slice] = best;
  }
}

__global__ void k_final(const unsigned long long* __restrict__ partials,
                        int* __restrict__ out) {
  int s = threadIdx.x;
  if (s < NUM_SEQS) {
    unsigned long long best = 0ull;
#pragma unroll
    for (int i = 0; i < NSLICE; ++i) {
      unsigned long long k = partials[s * NSLICE + i];
      if (k > best) best = k;
    }
    out[s] = (int)(~(unsigned)(best & 0xFFFFFFFFull));
  }
}

extern "C" void kernel_launch(void* const* d_in, const int* in_sizes, int n_in,
                              void* d_out, int out_size, void* d_ws, size_t ws_size,
                              hipStream_t stream) {
  const float* hs  = (const float*)d_in[0];   // [16384][4096] f32
  const float* W   = (const float*)d_in[1];   // [50257][4096] f32
  const int* lens  = (const int*)d_in[2];     // [32] i32

  char* ws = (char*)d_ws;
  int* idx = (int*)ws;
  float* hT = (float*)(ws + 1024);
  unsigned long long* partials = (unsigned long long*)(ws + 0x90000);
  float* part = (float*)(ws + (1 << 20));
  int* out = (int*)d_out;

  k_prep<<<1, 64, 0, stream>>>(lens, idx);
  k_gather<<<D_MODEL / 16, 512, 0, stream>>>(hs, idx, hT);
  dim3 grid(VP / 256, KSPLIT);
  k_logits_part<<<grid, 256, 0, stream>>>(W, hT, part);
  dim3 rgrid(NSLICE, NUM_SEQS);
  k_part_argmax<<<rgrid, 256, 0, stream>>>(part, partials);
  k_final<<<1, 64, 0, stream>>>(partials, out);
}